// Round 5
// baseline (115.265 us; speedup 1.0000x reference)
//
#include <hip/hip_runtime.h>
#include <cstdint>

#define BB 2
#define LL 2048
#define DD 1024
#define NN 16

// ---------------------------------------------------------------------------
// Kernel 1: projections, wave-shuffle version.
// out[4096,33] = seq[4096,1024] @ W^T,  W rows = [W_B(16); W_C(16); W_Delta].
// Block = 256 (4 waves), each wave owns 4 rows; lane owns 16 K-floats of all
// 4 rows (64 VGPR). Per W row: 4 coalesced float4 loads (wave reads the full
// 4KB row once -> total W L2 traffic 138 MB vs 553 MB at 1 row/thread),
// 64 FMA, then cluster-reduce(xor 1,2) + select p[lane&3] + butterfly(4..32).
// After reduce, lane l holds total for row (l&3); col collected at l>>2.
// ---------------------------------------------------------------------------
__global__ __launch_bounds__(256) void k_proj(
    const float* __restrict__ seq,
    const float* __restrict__ W_B, const float* __restrict__ b_B,
    const float* __restrict__ W_C, const float* __restrict__ b_C,
    const float* __restrict__ W_D, const float* __restrict__ b_D,
    const float* __restrict__ bias_D,
    float* __restrict__ Bm, float* __restrict__ Cm, float* __restrict__ Dl)
{
    const int tid  = threadIdx.x;
    const int wi   = tid >> 6;
    const int lane = tid & 63;
    const int rowb = blockIdx.x * 16 + wi * 4;

    const float* s0 = seq + (size_t)(rowb + 0) * DD;
    const float* s1 = seq + (size_t)(rowb + 1) * DD;
    const float* s2 = seq + (size_t)(rowb + 2) * DD;
    const float* s3 = seq + (size_t)(rowb + 3) * DD;

    float4 sv0[4], sv1[4], sv2[4], sv3[4];
    #pragma unroll
    for (int q = 0; q < 4; ++q) {
        const int off = q * 256 + lane * 4;
        sv0[q] = *(const float4*)&s0[off];
        sv1[q] = *(const float4*)&s1[off];
        sv2[q] = *(const float4*)&s2[off];
        sv3[q] = *(const float4*)&s3[off];
    }

    const bool bit0 = (lane & 1) != 0;
    const bool bit1 = (lane & 2) != 0;
    const int  colid = lane >> 2;       // 0..15

    float resb = 0.f, resc = 0.f, resd = 0.f;

    #pragma unroll
    for (int w = 0; w < 33; ++w) {
        const float* wr = (w < 16) ? (W_B + (size_t)w * DD)
                         : (w < 32) ? (W_C + (size_t)(w - 16) * DD)
                                    : W_D;
        float p0 = 0.f, p1 = 0.f, p2 = 0.f, p3 = 0.f;
        #pragma unroll
        for (int q = 0; q < 4; ++q) {
            float4 wv = *(const float4*)&wr[q * 256 + lane * 4];
            p0 = fmaf(sv0[q].x, wv.x, p0); p0 = fmaf(sv0[q].y, wv.y, p0);
            p0 = fmaf(sv0[q].z, wv.z, p0); p0 = fmaf(sv0[q].w, wv.w, p0);
            p1 = fmaf(sv1[q].x, wv.x, p1); p1 = fmaf(sv1[q].y, wv.y, p1);
            p1 = fmaf(sv1[q].z, wv.z, p1); p1 = fmaf(sv1[q].w, wv.w, p1);
            p2 = fmaf(sv2[q].x, wv.x, p2); p2 = fmaf(sv2[q].y, wv.y, p2);
            p2 = fmaf(sv2[q].z, wv.z, p2); p2 = fmaf(sv2[q].w, wv.w, p2);
            p3 = fmaf(sv3[q].x, wv.x, p3); p3 = fmaf(sv3[q].y, wv.y, p3);
            p3 = fmaf(sv3[q].z, wv.z, p3); p3 = fmaf(sv3[q].w, wv.w, p3);
        }
        // 4-lane cluster reduce
        p0 += __shfl_xor(p0, 1); p1 += __shfl_xor(p1, 1);
        p2 += __shfl_xor(p2, 1); p3 += __shfl_xor(p3, 1);
        p0 += __shfl_xor(p0, 2); p1 += __shfl_xor(p1, 2);
        p2 += __shfl_xor(p2, 2); p3 += __shfl_xor(p3, 2);
        // lane picks its row (lane&3)
        float pa = bit0 ? p1 : p0;
        float pb = bit0 ? p3 : p2;
        float v  = bit1 ? pb : pa;
        // butterfly across clusters (xor mask preserves lane&3)
        v += __shfl_xor(v, 4);
        v += __shfl_xor(v, 8);
        v += __shfl_xor(v, 16);
        v += __shfl_xor(v, 32);
        // collect
        if (w < 16)      { if (colid == w)      resb = v; }
        else if (w < 32) { if (colid == w - 16) resc = v; }
        else             resd = v;
    }

    // epilogue: lane l -> row (l&3), col (l>>2)
    const int r_o = lane & 3;
    Bm[(size_t)(rowb + r_o) * NN + colid] = resb + b_B[colid];
    Cm[(size_t)(rowb + r_o) * NN + colid] = resc + b_C[colid];
    if (lane < 4) {
        float z = resd + b_D[0] + bias_D[0];
        Dl[rowb + lane] = (z > 15.f) ? z : log1pf(__expf(z));
    }
}

// ---------------------------------------------------------------------------
// Kernel 2: per-chunk local scan (zero init). b,c from blockIdx only
// (wave-uniform -> scalar loads for Dl/Bm). 8-deep x batching.
// Sl layout: [b][c][d][n]; Gp: [b][c][d].
// ---------------------------------------------------------------------------
__global__ __launch_bounds__(256) void k_scan_local(
    const float* __restrict__ seq, const float* __restrict__ A,
    const float* __restrict__ Dl, const float* __restrict__ Bm,
    float* __restrict__ Gp, float* __restrict__ Sl, int C, int S)
{
    const int d = ((blockIdx.x & 3) << 8) | threadIdx.x;
    const int b = (blockIdx.x >> 2) & 1;
    const int c = blockIdx.x >> 3;

    const float A_d  = A[(size_t)d * NN];
    const float invA = 1.0f / A_d;

    float st[NN];
    #pragma unroll
    for (int n = 0; n < NN; ++n) st[n] = 0.f;
    float g = 1.f;

    const int l0 = c * S;
    const float*  xp = seq + ((size_t)b * LL + l0) * DD + d;
    const float*  dp = Dl + (size_t)b * LL + l0;
    const float4* bp = (const float4*)(Bm + ((size_t)b * LL + l0) * NN);

    for (int r0 = 0; r0 < S; r0 += 8) {
        float x8[8];
        #pragma unroll
        for (int i = 0; i < 8; ++i) x8[i] = xp[(size_t)(r0 + i) * DD];
        #pragma unroll
        for (int i = 0; i < 8; ++i) {
            const int rr = r0 + i;
            float delta = dp[rr];
            float4 b0 = bp[rr*4+0], b1 = bp[rr*4+1], b2 = bp[rr*4+2], b3 = bp[rr*4+3];
            float abar = __expf(A_d * delta);
            float u    = (abar - 1.f) * invA * x8[i];
            float bm[NN] = { b0.x,b0.y,b0.z,b0.w, b1.x,b1.y,b1.z,b1.w,
                             b2.x,b2.y,b2.z,b2.w, b3.x,b3.y,b3.z,b3.w };
            #pragma unroll
            for (int n = 0; n < NN; ++n) st[n] = fmaf(st[n], abar, u * bm[n]);
            g *= abar;
        }
    }

    Gp[((size_t)b * C + c) * DD + d] = g;
    float4* so = (float4*)(Sl + (((size_t)b * C + c) * DD + d) * NN);
    so[0] = make_float4(st[0],  st[1],  st[2],  st[3]);
    so[1] = make_float4(st[4],  st[5],  st[6],  st[7]);
    so[2] = make_float4(st[8],  st[9],  st[10], st[11]);
    so[3] = make_float4(st[12], st[13], st[14], st[15]);
}

// ---------------------------------------------------------------------------
// Kernel 3: prefix over chunks via LDS Hillis-Steele. One block per (b,d):
// 2048 elements (c x n) + 128 g's scanned in log2(C) rounds, ping-pong.
// Thread-minor indexing (e = i*256 + t) keeps all LDS accesses stride-1.
// ---------------------------------------------------------------------------
__global__ __launch_bounds__(256) void k_prefix(
    float* __restrict__ Sl, const float* __restrict__ Gp, int C)
{
    __shared__ float sA[128 * 16], sB[128 * 16];
    __shared__ float gA[128], gB[128];

    const int t = threadIdx.x;
    const int d = blockIdx.x & (DD - 1);
    const int b = blockIdx.x >> 10;
    const int E = (C * NN) >> 8;            // elements per thread

    for (int i = 0; i < E; ++i) {
        const int e = i * 256 + t;
        const int c = e >> 4, n = e & 15;
        sA[e] = Sl[(((size_t)b * C + c) * DD + d) * NN + n];
    }
    if (t < C) gA[t] = Gp[((size_t)b * C + t) * DD + d];
    __syncthreads();

    float* curS = sA; float* nxtS = sB;
    float* curG = gA; float* nxtG = gB;
    for (int dk = 1; dk < C; dk <<= 1) {
        for (int i = 0; i < E; ++i) {
            const int e = i * 256 + t;
            const int c = e >> 4;
            float s = curS[e];
            if (c >= dk) s = fmaf(curG[c], curS[e - (dk << 4)], s);
            nxtS[e] = s;
        }
        if (t < C) {
            float g = curG[t];
            if (t >= dk) g *= curG[t - dk];
            nxtG[t] = g;
        }
        __syncthreads();
        float* tp = curS; curS = nxtS; nxtS = tp;
        tp = curG; curG = nxtG; nxtG = tp;
    }

    for (int i = 0; i < E; ++i) {
        const int e = i * 256 + t;
        const int c = e >> 4, n = e & 15;
        Sl[(((size_t)b * C + c) * DD + d) * NN + n] = curS[e];
    }
}

// ---------------------------------------------------------------------------
// Kernel 4: final scan seeded with prefix state; emits y. 8-deep batching.
// ---------------------------------------------------------------------------
__global__ __launch_bounds__(256) void k_scan_out(
    const float* __restrict__ seq, const float* __restrict__ A,
    const float* __restrict__ Dl, const float* __restrict__ Bm,
    const float* __restrict__ Cm, const float* __restrict__ Sl,
    float* __restrict__ out, int C, int S)
{
    const int d = ((blockIdx.x & 3) << 8) | threadIdx.x;
    const int b = (blockIdx.x >> 2) & 1;
    const int c = blockIdx.x >> 3;

    const float A_d  = A[(size_t)d * NN];
    const float invA = 1.0f / A_d;

    float st[NN];
    if (c == 0) {
        #pragma unroll
        for (int n = 0; n < NN; ++n) st[n] = 0.f;
    } else {
        const float4* si = (const float4*)(
            Sl + (((size_t)b * C + (c - 1)) * DD + d) * NN);
        float4 v0 = si[0], v1 = si[1], v2 = si[2], v3 = si[3];
        st[0]=v0.x; st[1]=v0.y; st[2]=v0.z; st[3]=v0.w;
        st[4]=v1.x; st[5]=v1.y; st[6]=v1.z; st[7]=v1.w;
        st[8]=v2.x; st[9]=v2.y; st[10]=v2.z; st[11]=v2.w;
        st[12]=v3.x; st[13]=v3.y; st[14]=v3.z; st[15]=v3.w;
    }

    const int l0 = c * S;
    const float*  xp = seq + ((size_t)b * LL + l0) * DD + d;
    const float*  dp = Dl + (size_t)b * LL + l0;
    const float4* bp = (const float4*)(Bm + ((size_t)b * LL + l0) * NN);
    const float4* cp = (const float4*)(Cm + ((size_t)b * LL + l0) * NN);
    float* yp = out + ((size_t)b * LL + l0) * DD + d;

    for (int r0 = 0; r0 < S; r0 += 8) {
        float x8[8];
        #pragma unroll
        for (int i = 0; i < 8; ++i) x8[i] = xp[(size_t)(r0 + i) * DD];
        #pragma unroll
        for (int i = 0; i < 8; ++i) {
            const int rr = r0 + i;
            float delta = dp[rr];
            float4 b0 = bp[rr*4+0], b1 = bp[rr*4+1], b2 = bp[rr*4+2], b3 = bp[rr*4+3];
            float abar = __expf(A_d * delta);
            float u    = (abar - 1.f) * invA * x8[i];
            float bm[NN] = { b0.x,b0.y,b0.z,b0.w, b1.x,b1.y,b1.z,b1.w,
                             b2.x,b2.y,b2.z,b2.w, b3.x,b3.y,b3.z,b3.w };
            #pragma unroll
            for (int n = 0; n < NN; ++n) st[n] = fmaf(st[n], abar, u * bm[n]);

            float4 c0 = cp[rr*4+0], c1 = cp[rr*4+1], c2 = cp[rr*4+2], c3 = cp[rr*4+3];
            float cm[NN] = { c0.x,c0.y,c0.z,c0.w, c1.x,c1.y,c1.z,c1.w,
                             c2.x,c2.y,c2.z,c2.w, c3.x,c3.y,c3.z,c3.w };
            float y0 = 0.f, y1 = 0.f, y2 = 0.f, y3 = 0.f;
            #pragma unroll
            for (int n = 0; n < NN; n += 4) {
                y0 = fmaf(st[n+0], cm[n+0], y0);
                y1 = fmaf(st[n+1], cm[n+1], y1);
                y2 = fmaf(st[n+2], cm[n+2], y2);
                y3 = fmaf(st[n+3], cm[n+3], y3);
            }
            yp[(size_t)rr * DD] = (y0 + y1) + (y2 + y3);
        }
    }
}

extern "C" void kernel_launch(void* const* d_in, const int* in_sizes, int n_in,
                              void* d_out, int out_size, void* d_ws, size_t ws_size,
                              hipStream_t stream)
{
    const float* seq    = (const float*)d_in[0];
    const float* A      = (const float*)d_in[1];
    const float* W_B    = (const float*)d_in[2];
    const float* b_B    = (const float*)d_in[3];
    const float* W_C    = (const float*)d_in[4];
    const float* b_C    = (const float*)d_in[5];
    const float* W_D    = (const float*)d_in[6];
    const float* b_D    = (const float*)d_in[7];
    const float* bias_D = (const float*)d_in[8];
    float* out = (float*)d_out;
    float* ws  = (float*)d_ws;

    float* Bm = ws;                         // B*L*N
    float* Cm = Bm + (size_t)BB * LL * NN;  // B*L*N
    float* Dl = Cm + (size_t)BB * LL * NN;  // B*L
    float* Gp = Dl + (size_t)BB * LL;       // B*C*D

    int C = 128;
    while (C > 16) {
        size_t need = ((size_t)BB * LL * NN * 2 + (size_t)BB * LL +
                       (size_t)BB * DD * C * (1 + NN)) * sizeof(float);
        if (need <= ws_size) break;
        C >>= 1;
    }
    int S = LL / C;
    float* Sl = Gp + (size_t)BB * DD * C;   // B*C*D*N

    k_proj<<<(BB * LL) / 16, 256, 0, stream>>>(seq, W_B, b_B, W_C, b_C,
                                               W_D, b_D, bias_D, Bm, Cm, Dl);
    k_scan_local<<<(BB * DD * C) / 256, 256, 0, stream>>>(seq, A, Dl, Bm, Gp, Sl, C, S);
    k_prefix<<<BB * DD, 256, 0, stream>>>(Sl, Gp, C);
    k_scan_out<<<(BB * DD * C) / 256, 256, 0, stream>>>(seq, A, Dl, Bm, Cm, Sl, out, C, S);
}

// Round 6
// 66.003 us; speedup vs baseline: 1.7464x; 1.7464x over previous
//
#include <hip/hip_runtime.h>
#include <cstdint>

#define BB 2
#define LL 2048
#define DD 1024
#define NN 16
#define CC 128     // chunks per sequence
#define SS 16      // steps per chunk

// ---------------------------------------------------------------------------
// Kernel 1: projections, register-resident (R4 structure).
// out[4096,33] = seq[4096,1024] @ W^T,  W rows = [W_B(16); W_C(16); W_Delta].
// Block = 256 threads, 4 rows/block, grid = 1024.
// Thread (r = tid>>6, ks = tid&63) owns K cols {q*256 + ks*4 .. +3, q<4};
// all 33 W partial dots in registers; cross-lane reduce via one LDS pass.
// ---------------------------------------------------------------------------
#define PB 4

__global__ __launch_bounds__(256) void k_proj(
    const float* __restrict__ seq,
    const float* __restrict__ W_B, const float* __restrict__ b_B,
    const float* __restrict__ W_C, const float* __restrict__ b_C,
    const float* __restrict__ W_D, const float* __restrict__ b_D,
    const float* __restrict__ bias_D,
    float* __restrict__ Bm, float* __restrict__ Cm, float* __restrict__ Dl)
{
    __shared__ float red[256 * 34];

    const int tid = threadIdx.x;
    const int r   = tid >> 6;
    const int ks  = tid & 63;
    const int row = blockIdx.x * PB + r;

    const float* srow = seq + (size_t)row * DD;
    float4 sv[4];
    #pragma unroll
    for (int q = 0; q < 4; ++q)
        sv[q] = *(const float4*)&srow[q * 256 + ks * 4];

    float pb[16], pc[16], pd;

    #pragma unroll
    for (int w = 0; w < 16; ++w) {
        const float* wr = W_B + (size_t)w * DD;
        float a = 0.f;
        #pragma unroll
        for (int q = 0; q < 4; ++q) {
            float4 wv = *(const float4*)&wr[q * 256 + ks * 4];
            a = fmaf(sv[q].x, wv.x, a); a = fmaf(sv[q].y, wv.y, a);
            a = fmaf(sv[q].z, wv.z, a); a = fmaf(sv[q].w, wv.w, a);
        }
        pb[w] = a;
    }
    #pragma unroll
    for (int w = 0; w < 16; ++w) {
        const float* wr = W_C + (size_t)w * DD;
        float a = 0.f;
        #pragma unroll
        for (int q = 0; q < 4; ++q) {
            float4 wv = *(const float4*)&wr[q * 256 + ks * 4];
            a = fmaf(sv[q].x, wv.x, a); a = fmaf(sv[q].y, wv.y, a);
            a = fmaf(sv[q].z, wv.z, a); a = fmaf(sv[q].w, wv.w, a);
        }
        pc[w] = a;
    }
    {
        float a = 0.f;
        #pragma unroll
        for (int q = 0; q < 4; ++q) {
            float4 wv = *(const float4*)&W_D[q * 256 + ks * 4];
            a = fmaf(sv[q].x, wv.x, a); a = fmaf(sv[q].y, wv.y, a);
            a = fmaf(sv[q].z, wv.z, a); a = fmaf(sv[q].w, wv.w, a);
        }
        pd = a;
    }

    float* myrow = &red[tid * 34];
    #pragma unroll
    for (int w = 0; w < 16; ++w) myrow[w]      = pb[w];
    #pragma unroll
    for (int w = 0; w < 16; ++w) myrow[16 + w] = pc[w];
    myrow[32] = pd;
    __syncthreads();

    if (tid < PB * 33) {
        int r_o = tid / 33;
        int w_o = tid - r_o * 33;
        const float* base = &red[(r_o * 64) * 34 + w_o];
        float s = 0.f;
        #pragma unroll
        for (int k = 0; k < 64; ++k) s += base[k * 34];
        int rg = blockIdx.x * PB + r_o;
        if (w_o < 16) {
            Bm[(size_t)rg * NN + w_o] = s + b_B[w_o];
        } else if (w_o < 32) {
            Cm[(size_t)rg * NN + (w_o - 16)] = s + b_C[w_o - 16];
        } else {
            float z = s + b_D[0] + bias_D[0];
            Dl[rg] = (z > 15.f) ? z : log1pf(__expf(z));
        }
    }
}

// ---------------------------------------------------------------------------
// Kernel 2: per-chunk local scan. Uniform chunk data (Delta, Bm) staged in
// LDS once (coalesced burst), all 16 x-loads prefetched to registers, loop
// fully unrolled -> no VMEM and only broadcast ds_reads in the loop.
// Sl layout: [b][c][d][n]; Gp: [b][c][d].
// ---------------------------------------------------------------------------
__global__ __launch_bounds__(256) void k_scan_local(
    const float* __restrict__ seq, const float* __restrict__ A,
    const float* __restrict__ Dl, const float* __restrict__ Bm,
    float* __restrict__ Gp, float* __restrict__ Sl)
{
    __shared__ float  dlds[SS];
    __shared__ float4 blds[SS * 4];

    const int t = threadIdx.x;
    const int d = ((blockIdx.x & 3) << 8) | t;
    const int b = (blockIdx.x >> 2) & 1;
    const int c = blockIdx.x >> 3;
    const int l0 = c * SS;

    const float4* bp = (const float4*)(Bm + ((size_t)b * LL + l0) * NN);
    if (t < SS * 4)            blds[t]      = bp[t];
    else if (t < SS * 4 + SS)  dlds[t - SS * 4] = Dl[(size_t)b * LL + l0 + (t - SS * 4)];

    const float A_d  = A[(size_t)d * NN];
    const float invA = 1.0f / A_d;

    const float* xp = seq + ((size_t)b * LL + l0) * DD + d;
    float x16[SS];
    #pragma unroll
    for (int i = 0; i < SS; ++i) x16[i] = xp[(size_t)i * DD];

    float st[NN];
    #pragma unroll
    for (int n = 0; n < NN; ++n) st[n] = 0.f;
    float g = 1.f;

    __syncthreads();

    #pragma unroll
    for (int r = 0; r < SS; ++r) {
        float  delta = dlds[r];
        float4 b0 = blds[r*4+0], b1 = blds[r*4+1], b2 = blds[r*4+2], b3 = blds[r*4+3];
        float abar = __expf(A_d * delta);
        float u    = (abar - 1.f) * invA * x16[r];
        float bm[NN] = { b0.x,b0.y,b0.z,b0.w, b1.x,b1.y,b1.z,b1.w,
                         b2.x,b2.y,b2.z,b2.w, b3.x,b3.y,b3.z,b3.w };
        #pragma unroll
        for (int n = 0; n < NN; ++n) st[n] = fmaf(st[n], abar, u * bm[n]);
        g *= abar;
    }

    Gp[((size_t)b * CC + c) * DD + d] = g;
    float4* so = (float4*)(Sl + (((size_t)b * CC + c) * DD + d) * NN);
    so[0] = make_float4(st[0],  st[1],  st[2],  st[3]);
    so[1] = make_float4(st[4],  st[5],  st[6],  st[7]);
    so[2] = make_float4(st[8],  st[9],  st[10], st[11]);
    so[3] = make_float4(st[12], st[13], st[14], st[15]);
}

// ---------------------------------------------------------------------------
// Kernel 3: prefix over chunks via LDS Hillis-Steele; one block per (b,d).
// ---------------------------------------------------------------------------
__global__ __launch_bounds__(256) void k_prefix(
    float* __restrict__ Sl, const float* __restrict__ Gp)
{
    __shared__ float sA[CC * 16], sB[CC * 16];
    __shared__ float gA[CC], gB[CC];

    const int t = threadIdx.x;
    const int d = blockIdx.x & (DD - 1);
    const int b = blockIdx.x >> 10;
    const int E = (CC * NN) >> 8;

    for (int i = 0; i < E; ++i) {
        const int e = i * 256 + t;
        const int c = e >> 4, n = e & 15;
        sA[e] = Sl[(((size_t)b * CC + c) * DD + d) * NN + n];
    }
    if (t < CC) gA[t] = Gp[((size_t)b * CC + t) * DD + d];
    __syncthreads();

    float* curS = sA; float* nxtS = sB;
    float* curG = gA; float* nxtG = gB;
    for (int dk = 1; dk < CC; dk <<= 1) {
        for (int i = 0; i < E; ++i) {
            const int e = i * 256 + t;
            const int c = e >> 4;
            float s = curS[e];
            if (c >= dk) s = fmaf(curG[c], curS[e - (dk << 4)], s);
            nxtS[e] = s;
        }
        if (t < CC) {
            float g = curG[t];
            if (t >= dk) g *= curG[t - dk];
            nxtG[t] = g;
        }
        __syncthreads();
        float* tp = curS; curS = nxtS; nxtS = tp;
        tp = curG; curG = nxtG; nxtG = tp;
    }

    for (int i = 0; i < E; ++i) {
        const int e = i * 256 + t;
        const int c = e >> 4, n = e & 15;
        Sl[(((size_t)b * CC + c) * DD + d) * NN + n] = curS[e];
    }
}

// ---------------------------------------------------------------------------
// Kernel 4: final scan seeded with prefix state; emits y. Same staging as
// kernel 2 plus Cm slab; 16 prefetched x loads; fully unrolled.
// ---------------------------------------------------------------------------
__global__ __launch_bounds__(256) void k_scan_out(
    const float* __restrict__ seq, const float* __restrict__ A,
    const float* __restrict__ Dl, const float* __restrict__ Bm,
    const float* __restrict__ Cm, const float* __restrict__ Sl,
    float* __restrict__ out)
{
    __shared__ float  dlds[SS];
    __shared__ float4 blds[SS * 4];
    __shared__ float4 clds[SS * 4];

    const int t = threadIdx.x;
    const int d = ((blockIdx.x & 3) << 8) | t;
    const int b = (blockIdx.x >> 2) & 1;
    const int c = blockIdx.x >> 3;
    const int l0 = c * SS;

    const float4* bp = (const float4*)(Bm + ((size_t)b * LL + l0) * NN);
    const float4* cp = (const float4*)(Cm + ((size_t)b * LL + l0) * NN);
    if (t < SS * 4)                 blds[t] = bp[t];
    else if (t < SS * 8)            clds[t - SS * 4] = cp[t - SS * 4];
    else if (t < SS * 8 + SS)       dlds[t - SS * 8] = Dl[(size_t)b * LL + l0 + (t - SS * 8)];

    const float A_d  = A[(size_t)d * NN];
    const float invA = 1.0f / A_d;

    const float* xp = seq + ((size_t)b * LL + l0) * DD + d;
    float x16[SS];
    #pragma unroll
    for (int i = 0; i < SS; ++i) x16[i] = xp[(size_t)i * DD];

    float st[NN];
    if (c == 0) {
        #pragma unroll
        for (int n = 0; n < NN; ++n) st[n] = 0.f;
    } else {
        const float4* si = (const float4*)(
            Sl + (((size_t)b * CC + (c - 1)) * DD + d) * NN);
        float4 v0 = si[0], v1 = si[1], v2 = si[2], v3 = si[3];
        st[0]=v0.x; st[1]=v0.y; st[2]=v0.z; st[3]=v0.w;
        st[4]=v1.x; st[5]=v1.y; st[6]=v1.z; st[7]=v1.w;
        st[8]=v2.x; st[9]=v2.y; st[10]=v2.z; st[11]=v2.w;
        st[12]=v3.x; st[13]=v3.y; st[14]=v3.z; st[15]=v3.w;
    }

    float* yp = out + ((size_t)b * LL + l0) * DD + d;

    __syncthreads();

    #pragma unroll
    for (int r = 0; r < SS; ++r) {
        float  delta = dlds[r];
        float4 b0 = blds[r*4+0], b1 = blds[r*4+1], b2 = blds[r*4+2], b3 = blds[r*4+3];
        float abar = __expf(A_d * delta);
        float u    = (abar - 1.f) * invA * x16[r];
        float bm[NN] = { b0.x,b0.y,b0.z,b0.w, b1.x,b1.y,b1.z,b1.w,
                         b2.x,b2.y,b2.z,b2.w, b3.x,b3.y,b3.z,b3.w };
        #pragma unroll
        for (int n = 0; n < NN; ++n) st[n] = fmaf(st[n], abar, u * bm[n]);

        float4 c0 = clds[r*4+0], c1 = clds[r*4+1], c2 = clds[r*4+2], c3 = clds[r*4+3];
        float cm[NN] = { c0.x,c0.y,c0.z,c0.w, c1.x,c1.y,c1.z,c1.w,
                         c2.x,c2.y,c2.z,c2.w, c3.x,c3.y,c3.z,c3.w };
        float y0 = 0.f, y1 = 0.f, y2 = 0.f, y3 = 0.f;
        #pragma unroll
        for (int n = 0; n < NN; n += 4) {
            y0 = fmaf(st[n+0], cm[n+0], y0);
            y1 = fmaf(st[n+1], cm[n+1], y1);
            y2 = fmaf(st[n+2], cm[n+2], y2);
            y3 = fmaf(st[n+3], cm[n+3], y3);
        }
        yp[(size_t)r * DD] = (y0 + y1) + (y2 + y3);
    }
}

extern "C" void kernel_launch(void* const* d_in, const int* in_sizes, int n_in,
                              void* d_out, int out_size, void* d_ws, size_t ws_size,
                              hipStream_t stream)
{
    const float* seq    = (const float*)d_in[0];
    const float* A      = (const float*)d_in[1];
    const float* W_B    = (const float*)d_in[2];
    const float* b_B    = (const float*)d_in[3];
    const float* W_C    = (const float*)d_in[4];
    const float* b_C    = (const float*)d_in[5];
    const float* W_D    = (const float*)d_in[6];
    const float* b_D    = (const float*)d_in[7];
    const float* bias_D = (const float*)d_in[8];
    float* out = (float*)d_out;
    float* ws  = (float*)d_ws;

    // Workspace (floats): Bm(B*L*N) Cm(B*L*N) Dl(B*L) Gp(B*CC*D) Sl(B*CC*D*N)
    float* Bm = ws;
    float* Cm = Bm + (size_t)BB * LL * NN;
    float* Dl = Cm + (size_t)BB * LL * NN;
    float* Gp = Dl + (size_t)BB * LL;
    float* Sl = Gp + (size_t)BB * CC * DD;   // total ~18.9 MB, fits d_ws

    k_proj<<<(BB * LL) / PB, 256, 0, stream>>>(seq, W_B, b_B, W_C, b_C,
                                               W_D, b_D, bias_D, Bm, Cm, Dl);
    k_scan_local<<<(BB * DD * CC) / 256, 256, 0, stream>>>(seq, A, Dl, Bm, Gp, Sl);
    k_prefix<<<BB * DD, 256, 0, stream>>>(Sl, Gp);
    k_scan_out<<<(BB * DD * CC) / 256, 256, 0, stream>>>(seq, A, Dl, Bm, Cm, Sl, out);
}